// Round 1
// 521.026 us; speedup vs baseline: 1.4542x; 1.4542x over previous
//
#include <hip/hip_runtime.h>
#include <math.h>

#define BB 2
#define LL 2048
#define SS 2048
#define HH 8
#define EE 64
#define DD 64
#define HE (HH * EE)   // 512
// softmax scale = 1/sqrt(E) = 0.125

// ws layout (384 KB):
//   [0, 128K)     : m32  (B*H*L floats) -- BLAS-grid fp32 M_sp (bit-exact)
//   [128K, 256K)  : rank (B*H*L ints)
//   [256K, 384K)  : maxs (B*H*L floats)

typedef __attribute__((ext_vector_type(8))) short   bf16x8;   // MFMA A/B frag
typedef __attribute__((ext_vector_type(4))) float   f32x4;    // MFMA C/D frag
typedef __attribute__((ext_vector_type(8))) unsigned short u16x8;
typedef __attribute__((ext_vector_type(4))) unsigned short u16x4;

__device__ __forceinline__ unsigned short f2bf(float x) {   // fp32 -> bf16 RNE
    unsigned int u = __float_as_uint(x);
    return (unsigned short)((u + 0x7FFFu + ((u >> 16) & 1u)) >> 16);
}

// ---------- A: BLAS-grid fp32 M_sp, K staged via wave-private LDS dbuf ----
// Arithmetic sequence IDENTICAL to the verified R10/R11 kernel:
// score = sequential fmaf chain e=0..63 asc, single accumulator;
// row-sum = 8-acc pairwise base + exact-halves trees. DO NOT REORDER.
// Staging is an exact fp32 copy (global -> VGPR -> LDS), so every value and
// every add/fmaf happens in the identical order as before -> rank bit-exact.
//
// Structure: lane = query (64 q/block), wave w owns keys [w*512, w*512+512).
// Keys stream through per-wave double-buffered 16-key LDS chunks (4 KB each).
// Compute reads K via wave-uniform ds_read_b128 (LDS broadcast, in-order
// lgkmcnt, no bank conflicts). Global loads for chunk g+1 are issued BEFORE
// the compute of chunk g and ds_written AFTER it -> HBM latency hides under
// the ~2k-cycle fmaf body. No __syncthreads in the hot loop (wave-private).
__global__ __launch_bounds__(256, 2)
void msp_blas(const float* __restrict__ Q, const float* __restrict__ K,
              float* __restrict__ m32, float* __restrict__ maxs) {
#pragma clang fp contract(off)
    __shared__ __align__(16) float ldsK[4][2][16 * 64];   // 32 KB total

    const int bid = blockIdx.x;          // B*H*32 = 512
    const int lt = bid & 31, bh = bid >> 5;
    const int h = bh & 7, b = bh >> 3;
    const int t = threadIdx.x, lq = t & 63, w = t >> 6;
    const int l = lt * 64 + lq;

    float qf[64];
    const float4* qrow = (const float4*)(Q + (((size_t)b * LL + l) * HH + h) * EE);
#pragma unroll
    for (int i = 0; i < 16; i++) {
        float4 v = qrow[i];
        qf[4*i] = v.x; qf[4*i+1] = v.y; qf[4*i+2] = v.z; qf[4*i+3] = v.w;
    }

    const int wu = __builtin_amdgcn_readfirstlane(w);
    const float* Kb = K + (((size_t)b * SS) * HH + h) * EE;

    // staging map: lane covers key row (lq>>2) of the chunk, 64B starting at
    // float col (lq&3)*4; 4 loads of float4 at col +0,+16,+32,+48.
    const float* gstage = Kb + (size_t)(wu * 512 + (lq >> 2)) * HE + (lq & 3) * 4;
    const int lslot = (lq >> 2) * 64 + (lq & 3) * 4;   // LDS write base (floats)

    float4 pf0, pf1, pf2, pf3;
    // prologue: chunk 0 -> buf 0
    {
        const float* s = gstage;
        pf0 = *(const float4*)(s);
        pf1 = *(const float4*)(s + 16);
        pf2 = *(const float4*)(s + 32);
        pf3 = *(const float4*)(s + 48);
        float* d = &ldsK[wu][0][lslot];
        *(float4*)(d)      = pf0;
        *(float4*)(d + 16) = pf1;
        *(float4*)(d + 32) = pf2;
        *(float4*)(d + 48) = pf3;
    }

    float mx = -1e30f;
    float blk[4];
#pragma unroll 1
    for (int lf = 0; lf < 4; ++lf) {
        float r[8];
#pragma unroll 1
        for (int ch = 0; ch < 8; ++ch) {
            const int g = lf * 8 + ch;           // 16-key chunk index, 0..31
            const int gn = (g < 31) ? (g + 1) : 31;   // last iter: reload (discarded)

            // issue next-chunk global loads (land after compute, before ds_write)
            const float* s = gstage + (size_t)gn * (16 * HE);
            pf0 = *(const float4*)(s);
            pf1 = *(const float4*)(s + 16);
            pf2 = *(const float4*)(s + 32);
            pf3 = *(const float4*)(s + 48);

            const float* kb = &ldsK[wu][g & 1][0];
#pragma unroll 1
            for (int i2 = 0; i2 < 2; ++i2) {
                const int i8 = ch * 2 + i2;      // same i8 meaning as before
                float c[8];
#pragma unroll
                for (int j = 0; j < 8; j++) c[j] = 0.f;
#pragma unroll
                for (int e4 = 0; e4 < 16; ++e4) {
#pragma unroll
                    for (int j = 0; j < 8; j++) {
                        const float4 kv =
                            *(const float4*)&kb[(i2 * 8 + j) * 64 + e4 * 4];
                        c[j] = fmaf(qf[4*e4+0], kv.x, c[j]);
                        c[j] = fmaf(qf[4*e4+1], kv.y, c[j]);
                        c[j] = fmaf(qf[4*e4+2], kv.z, c[j]);
                        c[j] = fmaf(qf[4*e4+3], kv.w, c[j]);
                    }
                }
#pragma unroll
                for (int j = 0; j < 8; j++) {
                    mx = fmaxf(mx, c[j]);
                    if (i8 == 0) r[j] = c[j];
                    else         r[j] = __fadd_rn(r[j], c[j]);
                }
            }

            // write prefetched chunk g+1 into the other wave-private buffer
            float* d = &ldsK[wu][(g + 1) & 1][lslot];
            *(float4*)(d)      = pf0;
            *(float4*)(d + 16) = pf1;
            *(float4*)(d + 32) = pf2;
            *(float4*)(d + 48) = pf3;
        }
        blk[lf] = __fadd_rn(
            __fadd_rn(__fadd_rn(r[0], r[1]), __fadd_rn(r[2], r[3])),
            __fadd_rn(__fadd_rn(r[4], r[5]), __fadd_rn(r[6], r[7])));
    }
    const float sub = __fadd_rn(__fadd_rn(blk[0], blk[1]),
                                __fadd_rn(blk[2], blk[3]));

    __shared__ float smx[4][64], ssub[4][64];
    smx[w][lq] = mx; ssub[w][lq] = sub;
    __syncthreads();
    if (w == 0) {
        const float m_all = fmaxf(fmaxf(smx[0][lq], smx[1][lq]),
                                  fmaxf(smx[2][lq], smx[3][lq]));
        const float s2048 = __fadd_rn(__fadd_rn(ssub[0][lq], ssub[1][lq]),
                                      __fadd_rn(ssub[2][lq], ssub[3][lq]));
        const float mean = __fmul_rn(s2048, 0.00048828125f);  // /2048 exact
        m32[((size_t)bh << 11) + l]  = __fsub_rn(m_all, mean);
        maxs[((size_t)bh << 11) + l] = m_all;
    }
}

// ---------- B: descending sort, ties -> lower index first -----------------
__global__ __launch_bounds__(256)
void sort_rank(const float* __restrict__ m32, int* __restrict__ rank) {
    __shared__ unsigned int k1[2048];
    __shared__ int pay[2048];
    const int bh = blockIdx.x;
    const int t = threadIdx.x;
    for (int i = t; i < 2048; i += 256) {
        unsigned int u = __float_as_uint(m32[((size_t)bh << 11) + i]);
        u = (u & 0x80000000u) ? ~u : (u | 0x80000000u);
        k1[i] = u; pay[i] = i;
    }
    __syncthreads();
    for (int k = 2; k <= 2048; k <<= 1) {
        for (int j = k >> 1; j > 0; j >>= 1) {
            for (int i = t; i < 2048; i += 256) {
                const int ixj = i ^ j;
                if (ixj > i) {
                    unsigned int a1 = k1[i], c1 = k1[ixj];
                    int pa = pay[i], pc = pay[ixj];
                    const bool pre = (a1 > c1) || (a1 == c1 && pa < pc);
                    const bool dir = ((i & k) == 0);
                    if (dir != pre) {
                        k1[i] = c1; k1[ixj] = a1;
                        pay[i] = pc; pay[ixj] = pa;
                    }
                }
            }
            __syncthreads();
        }
    }
    for (int i = t; i < 2048; i += 256)
        rank[((size_t)bh << 11) + pay[i]] = i;   // inverse permutation
}

// ---------- C: bf16 MFMA flash (two-pass softmax), scatter by rank --------
// Wave w owns 16 queries (rows lt*64 + w*16 .. +15) over the FULL S range.
// Per 64-s chunk: QK via mfma_16x16x32_bf16 (8), exp, P->LDS (A-layout),
// PV via mfma (8). K staged [s][e], V staged transposed [d][s], pitch 72
// bf16 (16B-aligned rows, bank-spread).
__global__ __launch_bounds__(256, 2)
void flash_mfma(const float* __restrict__ Q, const float* __restrict__ K,
                const float* __restrict__ V, const float* __restrict__ maxs,
                const int* __restrict__ rank, float* __restrict__ out) {
    __shared__ unsigned short ldsK[64 * 72];        // 9216 B
    __shared__ unsigned short ldsVT[64 * 72];       // 9216 B  (V transposed)
    __shared__ unsigned short ldsP[4 * 16 * 72];    // 9216 B  (per-wave P)

    const int bid = blockIdx.x;          // 512
    const int lt = bid & 31, bh = bid >> 5;
    const int h = bh & 7, b = bh >> 3;
    const int t = threadIdx.x, lane = t & 63, w = t >> 6;
    const int quad = lane >> 4, cl = lane & 15;

    const size_t kvbase = (((size_t)b * SS) * HH + h) * EE;

    // Q A-frags: A[m=cl][k=quad*8+j (+32*ef)]
    bf16x8 qa[2];
    {
        const float* qp = Q + (((size_t)b * LL + (lt * 64 + w * 16 + cl)) * HH + h) * EE
                          + quad * 8;
#pragma unroll
        for (int ef = 0; ef < 2; ++ef) {
            float4 a0 = *(const float4*)(qp + ef * 32);
            float4 a1 = *(const float4*)(qp + ef * 32 + 4);
            short* s = (short*)&qa[ef];
            s[0] = (short)f2bf(a0.x); s[1] = (short)f2bf(a0.y);
            s[2] = (short)f2bf(a0.z); s[3] = (short)f2bf(a0.w);
            s[4] = (short)f2bf(a1.x); s[5] = (short)f2bf(a1.y);
            s[6] = (short)f2bf(a1.z); s[7] = (short)f2bf(a1.w);
        }
    }

    // per-lane row constants (rows quad*4+reg)
    float negpm[4];
    int rk[4];
#pragma unroll
    for (int reg = 0; reg < 4; ++reg) {
        const int qg = lt * 64 + w * 16 + quad * 4 + reg;
        negpm[reg] = -0.125f * maxs[((size_t)bh << 11) + qg];
        rk[reg]    = rank[((size_t)bh << 11) + qg];
    }

    f32x4 accO[4];
#pragma unroll
    for (int nt = 0; nt < 4; ++nt) accO[nt] = (f32x4){0.f, 0.f, 0.f, 0.f};
    float ell[4] = {0.f, 0.f, 0.f, 0.f};

    const int pbase = w * (16 * 72);

#pragma unroll 1
    for (int c0 = 0; c0 < SS; c0 += 64) {
        __syncthreads();
        // ---- stage K[s][e] -> bf16, row-major pitch 72 ----
        {
            const int row = t >> 2, col0 = (t & 3) * 16;
            const float* gp = K + kvbase + (size_t)(c0 + row) * HE + col0;
            float4 f0 = ((const float4*)gp)[0];
            float4 f1 = ((const float4*)gp)[1];
            float4 f2 = ((const float4*)gp)[2];
            float4 f3 = ((const float4*)gp)[3];
            u16x8 w0 = { f2bf(f0.x), f2bf(f0.y), f2bf(f0.z), f2bf(f0.w),
                         f2bf(f1.x), f2bf(f1.y), f2bf(f1.z), f2bf(f1.w) };
            u16x8 w1 = { f2bf(f2.x), f2bf(f2.y), f2bf(f2.z), f2bf(f2.w),
                         f2bf(f3.x), f2bf(f3.y), f2bf(f3.z), f2bf(f3.w) };
            *(u16x8*)&ldsK[row * 72 + col0]     = w0;
            *(u16x8*)&ldsK[row * 72 + col0 + 8] = w1;
        }
        // ---- stage V transposed: VT[d][s] bf16, pitch 72 ----
        {
            const int s0 = (t & 15) * 4, d0 = (t >> 4) * 4;
            const float* gv = V + kvbase + (size_t)(c0 + s0) * HE + d0;
            float4 v0 = *(const float4*)(gv);
            float4 v1 = *(const float4*)(gv + HE);
            float4 v2 = *(const float4*)(gv + 2 * HE);
            float4 v3 = *(const float4*)(gv + 3 * HE);
            u16x4 p0 = { f2bf(v0.x), f2bf(v1.x), f2bf(v2.x), f2bf(v3.x) };
            u16x4 p1 = { f2bf(v0.y), f2bf(v1.y), f2bf(v2.y), f2bf(v3.y) };
            u16x4 p2 = { f2bf(v0.z), f2bf(v1.z), f2bf(v2.z), f2bf(v3.z) };
            u16x4 p3 = { f2bf(v0.w), f2bf(v1.w), f2bf(v2.w), f2bf(v3.w) };
            *(u16x4*)&ldsVT[(d0 + 0) * 72 + s0] = p0;
            *(u16x4*)&ldsVT[(d0 + 1) * 72 + s0] = p1;
            *(u16x4*)&ldsVT[(d0 + 2) * 72 + s0] = p2;
            *(u16x4*)&ldsVT[(d0 + 3) * 72 + s0] = p3;
        }
        __syncthreads();

        // ---- QK^T: S[m=q16][n=s64] = A(Q) x B(K), B[k=e][n=s]=K[s][e] ----
        f32x4 Sc[4];
#pragma unroll
        for (int nt = 0; nt < 4; ++nt) {
            bf16x8 bk0 = *(const bf16x8*)&ldsK[(nt * 16 + cl) * 72 + quad * 8];
            bf16x8 bk1 = *(const bf16x8*)&ldsK[(nt * 16 + cl) * 72 + quad * 8 + 32];
            f32x4 z = (f32x4){0.f, 0.f, 0.f, 0.f};
            z = __builtin_amdgcn_mfma_f32_16x16x32_bf16(qa[0], bk0, z, 0, 0, 0);
            z = __builtin_amdgcn_mfma_f32_16x16x32_bf16(qa[1], bk1, z, 0, 0, 0);
            Sc[nt] = z;
        }

        // ---- softmax numerator + P (bf16) into A-layout LDS ----
#pragma unroll
        for (int nt = 0; nt < 4; ++nt) {
#pragma unroll
            for (int reg = 0; reg < 4; ++reg) {
                const float p = __expf(fmaf(Sc[nt][reg], 0.125f, negpm[reg]));
                ell[reg] += p;
                ldsP[pbase + (quad * 4 + reg) * 72 + nt * 16 + cl] = f2bf(p);
            }
        }

        // ---- PV: O[m=q16][n=d64] += A(P) x B(V), B[k=s][n=d]=VT[d][s] ----
        bf16x8 pa0 = *(const bf16x8*)&ldsP[pbase + cl * 72 + quad * 8];
        bf16x8 pa1 = *(const bf16x8*)&ldsP[pbase + cl * 72 + quad * 8 + 32];
#pragma unroll
        for (int nt = 0; nt < 4; ++nt) {
            bf16x8 bv0 = *(const bf16x8*)&ldsVT[(nt * 16 + cl) * 72 + quad * 8];
            bf16x8 bv1 = *(const bf16x8*)&ldsVT[(nt * 16 + cl) * 72 + quad * 8 + 32];
            accO[nt] = __builtin_amdgcn_mfma_f32_16x16x32_bf16(pa0, bv0, accO[nt], 0, 0, 0);
            accO[nt] = __builtin_amdgcn_mfma_f32_16x16x32_bf16(pa1, bv1, accO[nt], 0, 0, 0);
        }
    }

    // ---- ell: reduce across the 16 lanes sharing each row (within quad) ----
#pragma unroll
    for (int reg = 0; reg < 4; ++reg) {
        float e = ell[reg];
        e += __shfl_xor(e, 1);
        e += __shfl_xor(e, 2);
        e += __shfl_xor(e, 4);
        e += __shfl_xor(e, 8);
        ell[reg] = 1.0f / e;
    }

    // ---- scatter O rows by rank ----
#pragma unroll
    for (int reg = 0; reg < 4; ++reg) {
        float* orow = out + (((size_t)b * LL + rk[reg]) * HH + h) * DD;
#pragma unroll
        for (int nt = 0; nt < 4; ++nt)
            orow[nt * 16 + cl] = accO[nt][reg] * ell[reg];
    }
}

extern "C" void kernel_launch(void* const* d_in, const int* in_sizes, int n_in,
                              void* d_out, int out_size, void* d_ws, size_t ws_size,
                              hipStream_t stream) {
    const float* Q = (const float*)d_in[0];
    const float* K = (const float*)d_in[1];
    const float* V = (const float*)d_in[2];
    float* out = (float*)d_out;

    float* m32  = (float*)d_ws;                          // 128 KB
    int*   rank = (int*)((char*)d_ws + 131072);          // 128 KB
    float* maxs = (float*)((char*)d_ws + 262144);        // 128 KB

    msp_blas<<<BB * HH * (LL / 64), 256, 0, stream>>>(Q, K, m32, maxs);
    sort_rank<<<BB * HH, 256, 0, stream>>>(m32, rank);
    flash_mfma<<<BB * HH * (LL / 64), 256, 0, stream>>>(Q, K, V, maxs, rank, out);
}

// Round 2
// 489.791 us; speedup vs baseline: 1.5470x; 1.0638x over previous
//
#include <hip/hip_runtime.h>
#include <math.h>

#define BB 2
#define LL 2048
#define SS 2048
#define HH 8
#define EE 64
#define DD 64
#define HE (HH * EE)   // 512
// softmax scale = 1/sqrt(E) = 0.125

// ws layout (384 KB):
//   [0, 128K)     : m32  (B*H*L floats) -- BLAS-grid fp32 M_sp (bit-exact)
//   [128K, 256K)  : rank (B*H*L ints)
//   [256K, 384K)  : maxs (B*H*L floats)

typedef __attribute__((ext_vector_type(8))) short   bf16x8;   // MFMA A/B frag
typedef __attribute__((ext_vector_type(4))) float   f32x4;    // MFMA C/D frag
typedef __attribute__((ext_vector_type(8))) unsigned short u16x8;
typedef __attribute__((ext_vector_type(4))) unsigned short u16x4;

__device__ __forceinline__ unsigned short f2bf(float x) {   // fp32 -> bf16 RNE
    unsigned int u = __float_as_uint(x);
    return (unsigned short)((u + 0x7FFFu + ((u >> 16) & 1u)) >> 16);
}

// ---------- A: BLAS-grid fp32 M_sp, K via wave-uniform SMEM streaming -----
// Arithmetic sequence IDENTICAL to the verified kernel:
// score = sequential fmaf chain e=0..63 asc, single accumulator;
// r[j] chain over i8=0..15 sequential; blk = exact-halves tree over r[0..7];
// sub_w = ((blk[4w]+blk[4w+1])+(blk[4w+2]+blk[4w+3])); s2048 = tree over subs.
// DO NOT REORDER. Only the wave->blk assignment changed (16 waves x 1 blk
// instead of 4 waves x 4 blk) -- the combine tree is reproduced exactly.
//
// Structure: block = 1024 threads = 16 waves; lane = query (64 q/block);
// wave c owns the single 128-key blk [c*128, c*128+128). K addresses are
// wave-uniform (readfirstlane'd chunk) -> compiler emits s_load; K values are
// the scalar operand of fmaf (1 SGPR read per VALU instr is legal). Zero LDS
// traffic in the hot loop; 4 waves/SIMD of TLP cover the SMEM drain stalls.
__global__ __launch_bounds__(1024, 4)
void msp_blas(const float* __restrict__ Q, const float* __restrict__ K,
              float* __restrict__ m32, float* __restrict__ maxs) {
#pragma clang fp contract(off)
    __shared__ float smx[16][64], ssub[16][64];   // 8 KB

    const int bid = blockIdx.x;          // B*H*32 = 512
    const int lt = bid & 31, bh = bid >> 5;
    const int h = bh & 7, b = bh >> 3;
    const int t = threadIdx.x, lq = t & 63, w = t >> 6;   // w = 0..15
    const int l = lt * 64 + lq;

    float qf[64];
    const float4* qrow = (const float4*)(Q + (((size_t)b * LL + l) * HH + h) * EE);
#pragma unroll
    for (int i = 0; i < 16; i++) {
        float4 v = qrow[i];
        qf[4*i] = v.x; qf[4*i+1] = v.y; qf[4*i+2] = v.z; qf[4*i+3] = v.w;
    }

    // wave-uniform chunk index -> all K addresses scalar
    const int chunk = __builtin_amdgcn_readfirstlane(w);      // 0..15
    const float* Kc = K + (((size_t)b * SS) * HH + h) * EE
                        + (size_t)chunk * 128 * HE;

    float mx = -1e30f;
    float r[8];
#pragma unroll 1
    for (int i8 = 0; i8 < 16; ++i8) {
        float c[8];
#pragma unroll 1
        for (int jp = 0; jp < 4; ++jp) {
            // two keys processed together: two independent fmaf chains (ILP),
            // each chain e=0..63 ascending, single accumulator (bit-exact).
            const float* k0 = Kc + (size_t)(i8 * 8 + jp * 2) * HE;
            const float* k1 = k0 + HE;
            float c0 = 0.f, c1 = 0.f;
#pragma unroll
            for (int e4 = 0; e4 < 16; ++e4) {
                const float4 a = *(const float4*)(k0 + e4 * 4);
                const float4 d = *(const float4*)(k1 + e4 * 4);
                c0 = fmaf(qf[4*e4+0], a.x, c0);
                c0 = fmaf(qf[4*e4+1], a.y, c0);
                c0 = fmaf(qf[4*e4+2], a.z, c0);
                c0 = fmaf(qf[4*e4+3], a.w, c0);
                c1 = fmaf(qf[4*e4+0], d.x, c1);
                c1 = fmaf(qf[4*e4+1], d.y, c1);
                c1 = fmaf(qf[4*e4+2], d.z, c1);
                c1 = fmaf(qf[4*e4+3], d.w, c1);
            }
            c[jp*2]   = c0;
            c[jp*2+1] = c1;
        }
#pragma unroll
        for (int j = 0; j < 8; j++) {
            mx = fmaxf(mx, c[j]);
            if (i8 == 0) r[j] = c[j];
            else         r[j] = __fadd_rn(r[j], c[j]);
        }
    }
    // blk for this wave's 128-key chunk: exact-halves tree over r[0..7]
    const float blkv = __fadd_rn(
        __fadd_rn(__fadd_rn(r[0], r[1]), __fadd_rn(r[2], r[3])),
        __fadd_rn(__fadd_rn(r[4], r[5]), __fadd_rn(r[6], r[7])));

    smx[w][lq] = mx; ssub[w][lq] = blkv;
    __syncthreads();
    if (w == 0) {
        // m_all: fmax over 16 chunk-maxes (max is order-independent, exact)
        float m_all = smx[0][lq];
#pragma unroll
        for (int i = 1; i < 16; ++i) m_all = fmaxf(m_all, smx[i][lq]);
        // sub_w = ((blk[4w]+blk[4w+1])+(blk[4w+2]+blk[4w+3]))  -- old in-wave tree
        float subv[4];
#pragma unroll
        for (int ww = 0; ww < 4; ++ww)
            subv[ww] = __fadd_rn(
                __fadd_rn(ssub[4*ww+0][lq], ssub[4*ww+1][lq]),
                __fadd_rn(ssub[4*ww+2][lq], ssub[4*ww+3][lq]));
        const float s2048 = __fadd_rn(__fadd_rn(subv[0], subv[1]),
                                      __fadd_rn(subv[2], subv[3]));
        const float mean = __fmul_rn(s2048, 0.00048828125f);  // /2048 exact
        m32[((size_t)bh << 11) + l]  = __fsub_rn(m_all, mean);
        maxs[((size_t)bh << 11) + l] = m_all;
    }
}

// ---------- B: descending sort, ties -> lower index first -----------------
__global__ __launch_bounds__(256)
void sort_rank(const float* __restrict__ m32, int* __restrict__ rank) {
    __shared__ unsigned int k1[2048];
    __shared__ int pay[2048];
    const int bh = blockIdx.x;
    const int t = threadIdx.x;
    for (int i = t; i < 2048; i += 256) {
        unsigned int u = __float_as_uint(m32[((size_t)bh << 11) + i]);
        u = (u & 0x80000000u) ? ~u : (u | 0x80000000u);
        k1[i] = u; pay[i] = i;
    }
    __syncthreads();
    for (int k = 2; k <= 2048; k <<= 1) {
        for (int j = k >> 1; j > 0; j >>= 1) {
            for (int i = t; i < 2048; i += 256) {
                const int ixj = i ^ j;
                if (ixj > i) {
                    unsigned int a1 = k1[i], c1 = k1[ixj];
                    int pa = pay[i], pc = pay[ixj];
                    const bool pre = (a1 > c1) || (a1 == c1 && pa < pc);
                    const bool dir = ((i & k) == 0);
                    if (dir != pre) {
                        k1[i] = c1; k1[ixj] = a1;
                        pay[i] = pc; pay[ixj] = pa;
                    }
                }
            }
            __syncthreads();
        }
    }
    for (int i = t; i < 2048; i += 256)
        rank[((size_t)bh << 11) + pay[i]] = i;   // inverse permutation
}

// ---------- C: bf16 MFMA flash (two-pass softmax), scatter by rank --------
// Wave w owns 16 queries (rows lt*64 + w*16 .. +15) over the FULL S range.
// Per 64-s chunk: QK via mfma_16x16x32_bf16 (8), exp, P->LDS (A-layout),
// PV via mfma (8). K staged [s][e], V staged transposed [d][s], pitch 72
// bf16 (16B-aligned rows, bank-spread).
__global__ __launch_bounds__(256, 2)
void flash_mfma(const float* __restrict__ Q, const float* __restrict__ K,
                const float* __restrict__ V, const float* __restrict__ maxs,
                const int* __restrict__ rank, float* __restrict__ out) {
    __shared__ unsigned short ldsK[64 * 72];        // 9216 B
    __shared__ unsigned short ldsVT[64 * 72];       // 9216 B  (V transposed)
    __shared__ unsigned short ldsP[4 * 16 * 72];    // 9216 B  (per-wave P)

    const int bid = blockIdx.x;          // 512
    const int lt = bid & 31, bh = bid >> 5;
    const int h = bh & 7, b = bh >> 3;
    const int t = threadIdx.x, lane = t & 63, w = t >> 6;
    const int quad = lane >> 4, cl = lane & 15;

    const size_t kvbase = (((size_t)b * SS) * HH + h) * EE;

    // Q A-frags: A[m=cl][k=quad*8+j (+32*ef)]
    bf16x8 qa[2];
    {
        const float* qp = Q + (((size_t)b * LL + (lt * 64 + w * 16 + cl)) * HH + h) * EE
                          + quad * 8;
#pragma unroll
        for (int ef = 0; ef < 2; ++ef) {
            float4 a0 = *(const float4*)(qp + ef * 32);
            float4 a1 = *(const float4*)(qp + ef * 32 + 4);
            short* s = (short*)&qa[ef];
            s[0] = (short)f2bf(a0.x); s[1] = (short)f2bf(a0.y);
            s[2] = (short)f2bf(a0.z); s[3] = (short)f2bf(a0.w);
            s[4] = (short)f2bf(a1.x); s[5] = (short)f2bf(a1.y);
            s[6] = (short)f2bf(a1.z); s[7] = (short)f2bf(a1.w);
        }
    }

    // per-lane row constants (rows quad*4+reg)
    float negpm[4];
    int rk[4];
#pragma unroll
    for (int reg = 0; reg < 4; ++reg) {
        const int qg = lt * 64 + w * 16 + quad * 4 + reg;
        negpm[reg] = -0.125f * maxs[((size_t)bh << 11) + qg];
        rk[reg]    = rank[((size_t)bh << 11) + qg];
    }

    f32x4 accO[4];
#pragma unroll
    for (int nt = 0; nt < 4; ++nt) accO[nt] = (f32x4){0.f, 0.f, 0.f, 0.f};
    float ell[4] = {0.f, 0.f, 0.f, 0.f};

    const int pbase = w * (16 * 72);

#pragma unroll 1
    for (int c0 = 0; c0 < SS; c0 += 64) {
        __syncthreads();
        // ---- stage K[s][e] -> bf16, row-major pitch 72 ----
        {
            const int row = t >> 2, col0 = (t & 3) * 16;
            const float* gp = K + kvbase + (size_t)(c0 + row) * HE + col0;
            float4 f0 = ((const float4*)gp)[0];
            float4 f1 = ((const float4*)gp)[1];
            float4 f2 = ((const float4*)gp)[2];
            float4 f3 = ((const float4*)gp)[3];
            u16x8 w0 = { f2bf(f0.x), f2bf(f0.y), f2bf(f0.z), f2bf(f0.w),
                         f2bf(f1.x), f2bf(f1.y), f2bf(f1.z), f2bf(f1.w) };
            u16x8 w1 = { f2bf(f2.x), f2bf(f2.y), f2bf(f2.z), f2bf(f2.w),
                         f2bf(f3.x), f2bf(f3.y), f2bf(f3.z), f2bf(f3.w) };
            *(u16x8*)&ldsK[row * 72 + col0]     = w0;
            *(u16x8*)&ldsK[row * 72 + col0 + 8] = w1;
        }
        // ---- stage V transposed: VT[d][s] bf16, pitch 72 ----
        {
            const int s0 = (t & 15) * 4, d0 = (t >> 4) * 4;
            const float* gv = V + kvbase + (size_t)(c0 + s0) * HE + d0;
            float4 v0 = *(const float4*)(gv);
            float4 v1 = *(const float4*)(gv + HE);
            float4 v2 = *(const float4*)(gv + 2 * HE);
            float4 v3 = *(const float4*)(gv + 3 * HE);
            u16x4 p0 = { f2bf(v0.x), f2bf(v1.x), f2bf(v2.x), f2bf(v3.x) };
            u16x4 p1 = { f2bf(v0.y), f2bf(v1.y), f2bf(v2.y), f2bf(v3.y) };
            u16x4 p2 = { f2bf(v0.z), f2bf(v1.z), f2bf(v2.z), f2bf(v3.z) };
            u16x4 p3 = { f2bf(v0.w), f2bf(v1.w), f2bf(v2.w), f2bf(v3.w) };
            *(u16x4*)&ldsVT[(d0 + 0) * 72 + s0] = p0;
            *(u16x4*)&ldsVT[(d0 + 1) * 72 + s0] = p1;
            *(u16x4*)&ldsVT[(d0 + 2) * 72 + s0] = p2;
            *(u16x4*)&ldsVT[(d0 + 3) * 72 + s0] = p3;
        }
        __syncthreads();

        // ---- QK^T: S[m=q16][n=s64] = A(Q) x B(K), B[k=e][n=s]=K[s][e] ----
        f32x4 Sc[4];
#pragma unroll
        for (int nt = 0; nt < 4; ++nt) {
            bf16x8 bk0 = *(const bf16x8*)&ldsK[(nt * 16 + cl) * 72 + quad * 8];
            bf16x8 bk1 = *(const bf16x8*)&ldsK[(nt * 16 + cl) * 72 + quad * 8 + 32];
            f32x4 z = (f32x4){0.f, 0.f, 0.f, 0.f};
            z = __builtin_amdgcn_mfma_f32_16x16x32_bf16(qa[0], bk0, z, 0, 0, 0);
            z = __builtin_amdgcn_mfma_f32_16x16x32_bf16(qa[1], bk1, z, 0, 0, 0);
            Sc[nt] = z;
        }

        // ---- softmax numerator + P (bf16) into A-layout LDS ----
#pragma unroll
        for (int nt = 0; nt < 4; ++nt) {
#pragma unroll
            for (int reg = 0; reg < 4; ++reg) {
                const float p = __expf(fmaf(Sc[nt][reg], 0.125f, negpm[reg]));
                ell[reg] += p;
                ldsP[pbase + (quad * 4 + reg) * 72 + nt * 16 + cl] = f2bf(p);
            }
        }

        // ---- PV: O[m=q16][n=d64] += A(P) x B(V), B[k=s][n=d]=VT[d][s] ----
        bf16x8 pa0 = *(const bf16x8*)&ldsP[pbase + cl * 72 + quad * 8];
        bf16x8 pa1 = *(const bf16x8*)&ldsP[pbase + cl * 72 + quad * 8 + 32];
#pragma unroll
        for (int nt = 0; nt < 4; ++nt) {
            bf16x8 bv0 = *(const bf16x8*)&ldsVT[(nt * 16 + cl) * 72 + quad * 8];
            bf16x8 bv1 = *(const bf16x8*)&ldsVT[(nt * 16 + cl) * 72 + quad * 8 + 32];
            accO[nt] = __builtin_amdgcn_mfma_f32_16x16x32_bf16(pa0, bv0, accO[nt], 0, 0, 0);
            accO[nt] = __builtin_amdgcn_mfma_f32_16x16x32_bf16(pa1, bv1, accO[nt], 0, 0, 0);
        }
    }

    // ---- ell: reduce across the 16 lanes sharing each row (within quad) ----
#pragma unroll
    for (int reg = 0; reg < 4; ++reg) {
        float e = ell[reg];
        e += __shfl_xor(e, 1);
        e += __shfl_xor(e, 2);
        e += __shfl_xor(e, 4);
        e += __shfl_xor(e, 8);
        ell[reg] = 1.0f / e;
    }

    // ---- scatter O rows by rank ----
#pragma unroll
    for (int reg = 0; reg < 4; ++reg) {
        float* orow = out + (((size_t)b * LL + rk[reg]) * HH + h) * DD;
#pragma unroll
        for (int nt = 0; nt < 4; ++nt)
            orow[nt * 16 + cl] = accO[nt][reg] * ell[reg];
    }
}

extern "C" void kernel_launch(void* const* d_in, const int* in_sizes, int n_in,
                              void* d_out, int out_size, void* d_ws, size_t ws_size,
                              hipStream_t stream) {
    const float* Q = (const float*)d_in[0];
    const float* K = (const float*)d_in[1];
    const float* V = (const float*)d_in[2];
    float* out = (float*)d_out;

    float* m32  = (float*)d_ws;                          // 128 KB
    int*   rank = (int*)((char*)d_ws + 131072);          // 128 KB
    float* maxs = (float*)((char*)d_ws + 262144);        // 128 KB

    msp_blas<<<BB * HH * (LL / 64), 1024, 0, stream>>>(Q, K, m32, maxs);
    sort_rank<<<BB * HH, 256, 0, stream>>>(m32, rank);
    flash_mfma<<<BB * HH * (LL / 64), 256, 0, stream>>>(Q, K, V, maxs, rank, out);
}